// Round 3
// baseline (1173.361 us; speedup 1.0000x reference)
//
#include <hip/hip_runtime.h>
#include <stdint.h>

// ---------------- types ----------------
typedef __attribute__((ext_vector_type(8))) short bf16x8;   // 8 x bf16 = 4 VGPRs
typedef __attribute__((ext_vector_type(4))) short s16x4;    // 4 x bf16 = 8B
typedef __attribute__((ext_vector_type(4))) float f32x4;
typedef __attribute__((ext_vector_type(4))) unsigned u32x4;

#define AS1 __attribute__((address_space(1)))
#define AS3 __attribute__((address_space(3)))

static __device__ __forceinline__ void gload_lds16(const void* g, void* l) {
  __builtin_amdgcn_global_load_lds((const AS1 unsigned int*)g,
                                   (AS3 unsigned int*)l, 16, 0, 0);
}

// round-to-nearest-even f32 -> bf16 bits
static __device__ __forceinline__ short f2bs(float f) {
  unsigned u = __builtin_bit_cast(unsigned, f);
  unsigned r = (u + 0x7fffu + ((u >> 16) & 1u)) >> 16;
  return (short)r;
}
static __device__ __forceinline__ float bs2f(short s) {
  unsigned u = ((unsigned)(unsigned short)s) << 16;
  return __builtin_bit_cast(float, u);
}

static __device__ __forceinline__ float sigmoid_f(float x) {
  return 1.0f / (1.0f + __expf(-x));
}
static __device__ __forceinline__ float tanh_f(float x) {
  float ax = fabsf(x);
  float e  = __expf(-2.0f * ax);
  float t  = (1.0f - e) / (1.0f + e);
  return copysignf(t, x);
}

static __device__ __forceinline__ unsigned stale8(u32x4 a, u32x4 b, unsigned want) {
  return ((a[0] ^ want) | (a[1] ^ want) | (a[2] ^ want) | (a[3] ^ want) |
          (b[0] ^ want) | (b[1] ^ want) | (b[2] ^ want) | (b[3] ^ want)) & 0xffffu;
}

// constants
#define BATCH 256
#define HID   512
#define STEPS 256
#define G3    1536   // 3*HID

// ---------------- fp32 -> bf16 convert (weights) ----------------
__global__ __launch_bounds__(256) void convert_kernel(const float* __restrict__ src,
                                                      short* __restrict__ dst, int n4) {
  int i = blockIdx.x * 256 + threadIdx.x;
  if (i < n4) {
    float4 v = *(const float4*)(src + (size_t)i * 4);
    s16x4 o;
    o[0] = f2bs(v.x); o[1] = f2bs(v.y); o[2] = f2bs(v.z); o[3] = f2bs(v.w);
    *(s16x4*)(dst + (size_t)i * 4) = o;
  }
}

// ---------------- x[b][i][s] f32  ->  xT[s][b][i] bf16 ----------------
__global__ __launch_bounds__(256) void transpose_kernel(const float* __restrict__ x,
                                                        short* __restrict__ xT) {
  int bx = blockIdx.x;
  int st = bx & 7, it = (bx >> 3) & 15, b = bx >> 7;
  int s0 = st * 32, i0 = it * 32;
  int tid = threadIdx.x;
  __shared__ float tile[32][33];
  int il = tid >> 3, s4 = (tid & 7) * 4;
  float4 v = *(const float4*)(x + (size_t)b * 131072 + (size_t)(i0 + il) * 256 + s0 + s4);
  tile[il][s4 + 0] = v.x; tile[il][s4 + 1] = v.y;
  tile[il][s4 + 2] = v.z; tile[il][s4 + 3] = v.w;
  __syncthreads();
  int sl = tid >> 3, iv = (tid & 7) * 4;
  s16x4 o;
  o[0] = f2bs(tile[iv + 0][sl]); o[1] = f2bs(tile[iv + 1][sl]);
  o[2] = f2bs(tile[iv + 2][sl]); o[3] = f2bs(tile[iv + 3][sl]);
  *(s16x4*)(xT + (size_t)(s0 + sl) * 131072 + (size_t)b * 512 + i0 + iv) = o;
}

// ---------------- phase 1: gi[m][g] = xT[m] . W_ih[g] + bias_ih[g] (bf16 out) ----
__global__ __launch_bounds__(256) void phase1_kernel(const short* __restrict__ A,
                                                     const short* __restrict__ B,
                                                     const float* __restrict__ bias,
                                                     short* __restrict__ out, int M) {
  int MT = M >> 7;
  int bx = blockIdx.x;
  int mt = bx % MT, nt = bx / MT;
  int m0 = mt * 128, n0 = nt * 128;
  int tid = threadIdx.x, w = tid >> 6, lane = tid & 63;
  int lm = lane & 15, q = lane >> 4;
  int wm = w & 1, wn = w >> 1;
  __shared__ short As[128 * 32];
  __shared__ short Bs[128 * 32];
  f32x4 acc[4][4] = {};
  int srow = lane >> 2;
  int scol = (lane & 3) * 8;

  for (int kt = 0; kt < 16; ++kt) {
#pragma unroll
    for (int i2 = 0; i2 < 2; ++i2) {
      int i = w * 2 + i2;
      int row = i * 16 + srow;
      gload_lds16(A + (size_t)(m0 + row) * 512 + kt * 32 + scol, As + i * 512);
      gload_lds16(B + (size_t)(n0 + row) * 512 + kt * 32 + scol, Bs + i * 512);
    }
    __syncthreads();
    bf16x8 av[4], bv[4];
#pragma unroll
    for (int f = 0; f < 4; ++f) {
      av[f] = *(const bf16x8*)(As + (wm * 64 + f * 16 + lm) * 32 + q * 8);
      bv[f] = *(const bf16x8*)(Bs + (wn * 64 + f * 16 + lm) * 32 + q * 8);
    }
#pragma unroll
    for (int fm = 0; fm < 4; ++fm)
#pragma unroll
      for (int fn = 0; fn < 4; ++fn)
        acc[fm][fn] = __builtin_amdgcn_mfma_f32_16x16x32_bf16(av[fm], bv[fn], acc[fm][fn], 0, 0, 0);
    __syncthreads();
  }
#pragma unroll
  for (int fn = 0; fn < 4; ++fn) {
    int g = n0 + wn * 64 + fn * 16 + lm;
    float bi = bias[g];
#pragma unroll
    for (int fm = 0; fm < 4; ++fm) {
      int rb = m0 + wm * 64 + fm * 16 + q * 4;
#pragma unroll
      for (int r = 0; r < 4; ++r)
        out[(size_t)(rb + r) * G3 + g] = f2bs(acc[fm][fn][r] + bi);
    }
  }
}

// ---------------- phase 2: persistent GRU scan (split-K, frag-direct poll) ---
// 16 groups x 16 gate-slice blocks. Tagged-word publish protocol as R1
// (each dword = {bf16 h << 16 | step tag}; dword stores are single-copy
// atomic so value+tag never tear).
// Waves partition K (4 slices of 32 each) instead of gates: the poll loads
// land DIRECTLY in MFMA A-fragment layout (row=lane&15, cols k*32+(lane>>4)*8)
// so there is NO LDS h-stage, NO stash barrier, and all 4 waves do MFMA.
// Partial gh sums cross waves via a parity-double-buffered LDS buffer with
// ONE barrier per step.
// Poll shape = R1's known-good form: bulk 8-load round, whole-bundle retry,
// s_sleep(1) pacing (keeps 65k spinning threads from flooding the LLC with
// sc0/sc1 loads and starving publisher stores), bounded (wrong beats hang).
// Safety induction (as R1): publishes of tag t+1 happen only after the
// barrier that follows all 4 waves' polls of t, so any tag-t+2 write implies
// every block passed poll(t); part[] reuse distance is 2 steps, covered by
// the parity double buffer + the intervening barrier.
__global__ __launch_bounds__(256) void scan_kernel(const short* __restrict__ gi,
                                                   const short* __restrict__ Whh,
                                                   const float* __restrict__ bias_hh,
                                                   unsigned* __restrict__ hbuf,
                                                   float* __restrict__ hmaster,
                                                   int CH, int step_base, int first) {
  int bid = blockIdx.x;
  int group = (bid & 7) + 8 * ((bid >> 3) >> 4);
  int j = (bid >> 3) & 15;
  int tid = threadIdx.x;
  int w = tid >> 6, lane = tid & 63;
  int lm = lane & 15, q = lane >> 4;
  int grow = group * 16;

  __shared__ float part[12288];          // [2 parity][4 wave][6 n][64 lane][4]
  __shared__ float h_loc[512];           // [16 row][32 col] fp32 master slice
  __shared__ float bhh[96];

  // W_hh fragments: wave w owns K-slices {4w..4w+3}, all 6 N-tiles (96 VGPR)
  bf16x8 Wf[6][4];
#pragma unroll
  for (int n = 0; n < 6; ++n) {
    int g = n >> 1, ch = n & 1;
#pragma unroll
    for (int i = 0; i < 4; ++i) {
      int k = w * 4 + i;
      Wf[n][i] = *(const bf16x8*)(Whh + (size_t)(g * 512 + j * 32 + ch * 16 + lm) * 512 + k * 32 + q * 8);
    }
  }
  if (tid < 96) bhh[tid] = bias_hh[(tid >> 5) * 512 + j * 32 + (tid & 31)];
#pragma unroll
  for (int u = 0; u < 2; ++u) {
    int idx = tid + u * 256;
    int r = idx >> 5, cc = idx & 31;
    h_loc[idx] = first ? 0.0f : hmaster[(size_t)(grow + r) * 512 + j * 32 + cc];
  }
  __syncthreads();

  // per-thread gi pointers (2 elements per thread per gate), bf16
  int i0 = tid, i1 = tid + 256;
  const short* gp0 = gi + (size_t)(grow + (i0 >> 5)) * G3 + j * 32 + (i0 & 31);
  const short* gp1 = gi + (size_t)(grow + (i1 >> 5)) * G3 + j * 32 + (i1 & 31);
  const size_t gstride = (size_t)256 * G3;
  short pg0r = gp0[0], pg0z = gp0[512], pg0n = gp0[1024];
  short pg1r = gp1[0], pg1z = gp1[512], pg1n = gp1[1024];

  unsigned* grp = hbuf + (size_t)group * 8192;
  // per-lane byte offset of slice (4w+i): row lm, col bytes k*128 + q*32
  unsigned o0 = (unsigned)(lm * 2048 + w * 512 + q * 32);
  unsigned o1 = o0 + 128, o2 = o0 + 256, o3 = o0 + 384;

  for (int t = 0; t < CH; ++t) {
    int gstep = step_base + t;
    int p = gstep & 1;
    const unsigned* src = grp + (size_t)p * 131072;
    unsigned want = (unsigned)gstep & 0xffffu;

    // ---- poll: bulk 8-load (2 dwordx4 per K-slice), whole-bundle retry with
    // s_sleep pacing. waitcnt INSIDE the asm so the tag check can never be
    // hoisted above the wait.
    u32x4 v0, v1, v2, v3, v4, v5, v6, v7;
    int spin = 0;
    for (;;) {
      asm volatile(
          "global_load_dwordx4 %0, %8, %12 sc0 sc1\n\t"
          "global_load_dwordx4 %1, %8, %12 offset:16 sc0 sc1\n\t"
          "global_load_dwordx4 %2, %9, %12 sc0 sc1\n\t"
          "global_load_dwordx4 %3, %9, %12 offset:16 sc0 sc1\n\t"
          "global_load_dwordx4 %4, %10, %12 sc0 sc1\n\t"
          "global_load_dwordx4 %5, %10, %12 offset:16 sc0 sc1\n\t"
          "global_load_dwordx4 %6, %11, %12 sc0 sc1\n\t"
          "global_load_dwordx4 %7, %11, %12 offset:16 sc0 sc1\n\t"
          "s_waitcnt vmcnt(0)"
          : "=&v"(v0), "=&v"(v1), "=&v"(v2), "=&v"(v3),
            "=&v"(v4), "=&v"(v5), "=&v"(v6), "=&v"(v7)
          : "v"(o0), "v"(o1), "v"(o2), "v"(o3), "s"(src)
          : "memory");
      unsigned d = stale8(v0, v1, want) | stale8(v2, v3, want) |
                   stale8(v4, v5, want) | stale8(v6, v7, want);
      if (d == 0u || ++spin > (1 << 15)) break;
      __builtin_amdgcn_s_sleep(1);
    }

    f32x4 acc[6] = {};

#define SLICE(ii, VA, VB)                                                     \
    {                                                                         \
      bf16x8 a;                                                               \
      a[0] = (short)(VA[0] >> 16); a[1] = (short)(VA[1] >> 16);               \
      a[2] = (short)(VA[2] >> 16); a[3] = (short)(VA[3] >> 16);               \
      a[4] = (short)(VB[0] >> 16); a[5] = (short)(VB[1] >> 16);               \
      a[6] = (short)(VB[2] >> 16); a[7] = (short)(VB[3] >> 16);               \
      _Pragma("unroll")                                                       \
      for (int n = 0; n < 6; ++n)                                             \
        acc[n] = __builtin_amdgcn_mfma_f32_16x16x32_bf16(a, Wf[n][ii], acc[n], 0, 0, 0); \
    }

    SLICE(0, v0, v1)
    SLICE(1, v2, v3)
    SLICE(2, v4, v5)
    SLICE(3, v6, v7)
#undef SLICE

    // consume current gi prefetch; issue next step's (hides under barrier/cell)
    float cg0r = bs2f(pg0r), cg0z = bs2f(pg0z), cg0n = bs2f(pg0n);
    float cg1r = bs2f(pg1r), cg1z = bs2f(pg1z), cg1n = bs2f(pg1n);
    {
      size_t o = (size_t)((t + 1 < CH) ? (t + 1) : t) * gstride;
      pg0r = gp0[o]; pg0z = gp0[o + 512]; pg0n = gp0[o + 1024];
      pg1r = gp1[o]; pg1z = gp1[o + 512]; pg1n = gp1[o + 1024];
    }

    // partial gh -> LDS (parity double buffer), one barrier
    {
      float* pw = part + p * 6144 + w * 1536 + lane * 4;
#pragma unroll
      for (int n = 0; n < 6; ++n)
        *(f32x4*)(pw + n * 256) = acc[n];
    }
    __syncthreads();

    // elementwise GRU cell (sum 4 wave-partials in-register) + tagged publish
    unsigned tagp = (unsigned)(gstep + 1);
    unsigned* dstb = grp + (size_t)(1 - p) * 131072;

#define CELL(EE, CGR, CGZ, CGN)                                               \
    {                                                                         \
      int row = (EE) >> 5, colh = (EE) & 31;                                  \
      const float* pp = part + p * 6144 + ((row >> 2) * 16 + (colh & 15)) * 4 \
                        + (row & 3);                                          \
      int nr = colh >> 4;                                                     \
      float sr = 0.f, sz = 0.f, sn = 0.f;                                     \
      _Pragma("unroll")                                                       \
      for (int ww = 0; ww < 4; ++ww) {                                        \
        const float* qq = pp + ww * 1536;                                     \
        sr += qq[nr * 256]; sz += qq[(2 + nr) * 256]; sn += qq[(4 + nr) * 256]; \
      }                                                                       \
      float hr = sr + bhh[colh], hz = sz + bhh[32 + colh], hn = sn + bhh[64 + colh]; \
      float rr = sigmoid_f(CGR + hr);                                         \
      float zz = sigmoid_f(CGZ + hz);                                         \
      float nn = tanh_f(CGN + rr * hn);                                       \
      float hv = (1.0f - zz) * nn + zz * h_loc[EE];                           \
      h_loc[EE] = hv;                                                         \
      unsigned val = (((unsigned)(unsigned short)f2bs(hv)) << 16) | tagp;     \
      unsigned* dp = dstb + row * 512 + j * 32 + colh;                        \
      asm volatile("global_store_dword %0, %1, off sc0 sc1" :: "v"(dp), "v"(val) : "memory"); \
    }

    CELL(i0, cg0r, cg0z, cg0n)
    CELL(i1, cg1r, cg1z, cg1n)
#undef CELL
  }

  // write fp32 state back (d_out doubles as h_master across chunk launches)
#pragma unroll
  for (int u = 0; u < 2; ++u) {
    int idx = tid + u * 256;
    int r = idx >> 5, cc = idx & 31;
    hmaster[(size_t)(grow + r) * 512 + j * 32 + cc] = h_loc[idx];
  }
}

// ---------------- host ----------------
extern "C" void kernel_launch(void* const* d_in, const int* in_sizes, int n_in,
                              void* d_out, int out_size, void* d_ws, size_t ws_size,
                              hipStream_t stream) {
  const float* x   = (const float*)d_in[0];
  const float* Wih = (const float*)d_in[1];
  const float* Whh = (const float*)d_in[2];
  const float* bih = (const float*)d_in[3];
  const float* bhh = (const float*)d_in[4];
  float* out = (float*)d_out;
  char* ws = (char*)d_ws;

  const size_t XT_BYTES   = (size_t)256 * 256 * 512 * 2;  // 64 MiB
  const size_t W_BYTES    = (size_t)1536 * 512 * 2;       // 1.5 MiB
  const size_t HBUF_BYTES = (size_t)2 * 256 * 512 * 4;    // 1 MiB (tagged dwords)
  const size_t FIXED = XT_BYTES + 2 * W_BYTES + HBUF_BYTES + 4096;

  int CH = 256;
  while (CH > 4 && FIXED + (size_t)CH * 256 * G3 * 2 > ws_size) CH >>= 1;

  size_t off = 0;
  short* gi = (short*)(ws + off);          off += (size_t)CH * 256 * G3 * 2;
  short* xT = (short*)(ws + off);          off += XT_BYTES;
  short* WihB = (short*)(ws + off);        off += W_BYTES;
  short* WhhB = (short*)(ws + off);        off += W_BYTES;
  unsigned* hbuf = (unsigned*)(ws + off);

  hipMemsetAsync(hbuf, 0, HBUF_BYTES, stream);

  convert_kernel<<<768, 256, 0, stream>>>(Wih, WihB, 196608);
  convert_kernel<<<768, 256, 0, stream>>>(Whh, WhhB, 196608);
  transpose_kernel<<<32768, 256, 0, stream>>>(x, xT);

  int nch = 256 / CH;
  for (int c = 0; c < nch; ++c) {
    int M = CH * 256;
    phase1_kernel<<<(M / 128) * 12, 256, 0, stream>>>(
        xT + (size_t)c * CH * 256 * 512, WihB, bih, gi, M);
    scan_kernel<<<256, 256, 0, stream>>>(gi, WhhB, bhh, hbuf, out,
                                         CH, c * CH, c == 0 ? 1 : 0);
  }
}